// Round 1
// baseline (244.058 us; speedup 1.0000x reference)
//
#include <hip/hip_runtime.h>
#include <math.h>

// Problem constants (fixed by the reference)
#define BATCH 16
#define CH 3
#define H 512
#define W 512
#define HW (H * W)            // 262144
#define NIMG (BATCH * CH)     // 48
#define TOTAL (NIMG * HW)     // 12582912

// Affine theta entries (normalized coords), f32 of the Python doubles.
// Order as applied: mirror, translate, scale, zoom, rotate, shear.
#define COS_R 0.8910065241883679f
#define SIN_R 0.45399049973954675f

// One bilinear affine warp (zeros padding, align_corners=False), matching
// torch/JAX grid_sample semantics in the reference.
__global__ void warp_bilinear(const float* __restrict__ in, float* __restrict__ out,
                              float a, float b, float c, float d, float e, float f) {
    int stride = gridDim.x * blockDim.x;
    for (int idx = blockIdx.x * blockDim.x + threadIdx.x; idx < TOTAL; idx += stride) {
        int wx = idx & (W - 1);
        int wy = (idx >> 9) & (H - 1);
        int img = idx >> 18;

        float x = (wx + 0.5f) * (2.0f / W) - 1.0f;
        float y = (wy + 0.5f) * (2.0f / H) - 1.0f;
        float gx = a * x + b * y + c;
        float gy = d * x + e * y + f;
        float ix = ((gx + 1.0f) * W - 1.0f) * 0.5f;
        float iy = ((gy + 1.0f) * H - 1.0f) * 0.5f;

        float x0f = floorf(ix), y0f = floorf(iy);
        float wx1 = ix - x0f, wx0 = 1.0f - wx1;
        float wy1 = iy - y0f, wy0 = 1.0f - wy1;
        int x0 = (int)x0f, y0 = (int)y0f;
        int x1 = x0 + 1, y1 = y0 + 1;

        const float* base = in + img * HW;
        bool vx0 = (unsigned)x0 < (unsigned)W;
        bool vx1 = (unsigned)x1 < (unsigned)W;
        bool vy0 = (unsigned)y0 < (unsigned)H;
        bool vy1 = (unsigned)y1 < (unsigned)H;

        float v00 = (vx0 && vy0) ? base[y0 * W + x0] : 0.0f;
        float v01 = (vx1 && vy0) ? base[y0 * W + x1] : 0.0f;
        float v10 = (vx0 && vy1) ? base[y1 * W + x0] : 0.0f;
        float v11 = (vx1 && vy1) ? base[y1 * W + x1] : 0.0f;

        out[idx] = v00 * (wy0 * wx0) + v01 * (wy0 * wx1)
                 + v10 * (wy1 * wx0) + v11 * (wy1 * wx1);
    }
}

// Compose the 6 nearest-neighbor integer maps (exact vs sequential resampling).
// Apply stage 6's map first (shear), then 5 (rotate), ... then 1 (mirror).
__global__ void compose_nearest_map(int* __restrict__ map) {
    int p = blockIdx.x * blockDim.x + threadIdx.x;
    if (p >= HW) return;

    // thetas in REVERSE application order: shear, rotate, zoom, scale, translate, mirror
    const float TH[6][6] = {
        { 1.0f,  0.05f, 0.0f,  -0.03f, 1.0f,  0.0f },   // shear
        { COS_R, -SIN_R, 0.0f,  SIN_R, COS_R, 0.0f },   // rotate
        { 0.9f,  0.0f,  0.0f,   0.0f,  0.9f,  0.0f },   // zoom
        { 1.1f,  0.0f,  0.0f,   0.0f,  0.95f, 0.0f },   // scale
        { 1.0f,  0.0f,  0.06f,  0.0f,  1.0f, -0.04f },  // translate
        { -1.0f, 0.0f,  0.0f,   0.0f,  1.0f,  0.0f },   // mirror
    };

    int cx = p & (W - 1);
    int cy = p >> 9;
    bool valid = true;
    #pragma unroll
    for (int s = 0; s < 6; ++s) {
        if (!valid) break;
        float x = (cx + 0.5f) * (2.0f / W) - 1.0f;
        float y = (cy + 0.5f) * (2.0f / H) - 1.0f;
        float gx = TH[s][0] * x + TH[s][1] * y + TH[s][2];
        float gy = TH[s][3] * x + TH[s][4] * y + TH[s][5];
        float ix = ((gx + 1.0f) * W - 1.0f) * 0.5f;
        float iy = ((gy + 1.0f) * H - 1.0f) * 0.5f;
        float xr = rintf(ix);   // round half to even == jnp.round
        float yr = rintf(iy);
        if (xr < 0.0f || xr > (float)(W - 1) || yr < 0.0f || yr > (float)(H - 1)) {
            valid = false;
        } else {
            cx = (int)xr;
            cy = (int)yr;
        }
    }
    map[p] = valid ? (cy * W + cx) : -1;
}

// One gather pass applies the composed nearest map to all 48 label planes.
__global__ void gather_label(const float* __restrict__ in, const int* __restrict__ map,
                             float* __restrict__ out) {
    int stride = gridDim.x * blockDim.x;
    for (int idx = blockIdx.x * blockDim.x + threadIdx.x; idx < TOTAL; idx += stride) {
        int p = idx & (HW - 1);
        int img = idx >> 18;
        int m = map[p];
        out[idx] = (m >= 0) ? in[img * HW + m] : 0.0f;
    }
}

extern "C" void kernel_launch(void* const* d_in, const int* in_sizes, int n_in,
                              void* d_out, int out_size, void* d_ws, size_t ws_size,
                              hipStream_t stream) {
    const float* img_in = (const float*)d_in[0];
    const float* lab_in = (const float*)d_in[1];
    float* out_img = (float*)d_out;           // first TOTAL floats
    float* out_lab = (float*)d_out + TOTAL;   // second TOTAL floats

    float* ws_img = (float*)d_ws;             // TOTAL floats ping-pong buffer
    int* map = (int*)((float*)d_ws + TOTAL);  // HW ints

    const int BLK = 256;
    const int GRID = 2048;                     // grid-stride over TOTAL
    const int MAP_GRID = (HW + BLK - 1) / BLK; // 1024

    // --- label path: compose map once, gather once (exact) ---
    compose_nearest_map<<<MAP_GRID, BLK, 0, stream>>>(map);
    gather_label<<<GRID, BLK, 0, stream>>>(lab_in, map, out_lab);

    // --- img path: 6 sequential bilinear warps, ping-pong ws <-> out_img ---
    // stage 1: mirror      in -> ws
    warp_bilinear<<<GRID, BLK, 0, stream>>>(img_in, ws_img,
        -1.0f, 0.0f, 0.0f,   0.0f, 1.0f, 0.0f);
    // stage 2: translate   ws -> out
    warp_bilinear<<<GRID, BLK, 0, stream>>>(ws_img, out_img,
         1.0f, 0.0f, 0.06f,  0.0f, 1.0f, -0.04f);
    // stage 3: scale       out -> ws
    warp_bilinear<<<GRID, BLK, 0, stream>>>(out_img, ws_img,
         1.1f, 0.0f, 0.0f,   0.0f, 0.95f, 0.0f);
    // stage 4: zoom        ws -> out
    warp_bilinear<<<GRID, BLK, 0, stream>>>(ws_img, out_img,
         0.9f, 0.0f, 0.0f,   0.0f, 0.9f, 0.0f);
    // stage 5: rotate      out -> ws
    warp_bilinear<<<GRID, BLK, 0, stream>>>(out_img, ws_img,
         COS_R, -SIN_R, 0.0f,  SIN_R, COS_R, 0.0f);
    // stage 6: shear       ws -> out
    warp_bilinear<<<GRID, BLK, 0, stream>>>(ws_img, out_img,
         1.0f, 0.05f, 0.0f,  -0.03f, 1.0f, 0.0f);
}